// Round 5
// baseline (637.540 us; speedup 1.0000x reference)
//
#include <hip/hip_runtime.h>
#include <hip/hip_bf16.h>

#define NHD 8
#define HD  32
#define C_  256
#define TD_ 512
#define S_  256
#define N_  32768   // D*H*W
#define B_  2

typedef short bf16x8 __attribute__((ext_vector_type(8)));
typedef short bf16x4 __attribute__((ext_vector_type(4)));
typedef float f32x4  __attribute__((ext_vector_type(4)));

#define MFMA16(a,b,c) __builtin_amdgcn_mfma_f32_16x16x32_bf16(a,b,c,0,0,0)

__device__ __forceinline__ short f2bf(float f){
    __hip_bfloat16 h = __float2bfloat16(f);
    return *reinterpret_cast<short*>(&h);
}

// ---------------------------------------------------------------------------
// prep_fvt: fv f32 [b][c][n] -> fvt bf16 [b][n][c]. Tile 64c x 128n.
// LDS Ts[64][128] bf16, XOR-swizzled on 4-short units: u' = u ^ (c&31).
// Reads: coalesced float4 along n. Writes: 8 lanes x b128 = 128B/row contig.
// ---------------------------------------------------------------------------
__global__ __launch_bounds__(256) void prep_fvt(
    const float* __restrict__ fv, short* __restrict__ fvt)
{
    __shared__ short Ts[64 * 128];   // 16 KB
    const int t = threadIdx.x;
    const int n0 = blockIdx.x * 128, c0 = blockIdx.y * 64, b = blockIdx.z;

#pragma unroll
    for (int i = 0; i < 8; ++i) {
        int c_loc = (t >> 5) + 8 * i;           // 0..63
        int u = t & 31;                          // n-unit (4 floats)
        float4 v = *(const float4*)&fv[(size_t)(b * C_ + c0 + c_loc) * N_ + n0 + u * 4];
        int up = u ^ (c_loc & 31);
        bf16x4 s4 = { f2bf(v.x), f2bf(v.y), f2bf(v.z), f2bf(v.w) };
        *(bf16x4*)&Ts[c_loc * 128 + up * 4] = s4;
    }
    __syncthreads();
#pragma unroll
    for (int i = 0; i < 4; ++i) {
        int n = (t >> 3) + 32 * i;               // 0..127
        bf16x8 r;
#pragma unroll
        for (int k = 0; k < 8; ++k) {
            int c = (t & 7) * 8 + k;             // 0..63
            int up = (n >> 2) ^ (c & 31);
            r[k] = Ts[c * 128 + up * 4 + (n & 3)];
        }
        *(bf16x8*)&fvt[((size_t)b * N_ + n0 + n) * 256 + c0 + (t & 7) * 8] = r;
    }
}

// ---------------------------------------------------------------------------
// prep_w: transpose q_w, o_w (fp32 [c][co]) -> bf16 W^T [co][c]  (verified R3)
// ---------------------------------------------------------------------------
__global__ __launch_bounds__(256) void prep_w(
    const float* __restrict__ qw, const float* __restrict__ ow,
    short* __restrict__ wtq, short* __restrict__ wto)
{
    int gid = blockIdx.x * 256 + threadIdx.x;
    int m = gid >> 16;
    int e = gid & 65535;
    int c = e >> 8, co = e & 255;
    const float* src = m ? ow : qw;
    short* dst = m ? wto : wtq;
    dst[co * 256 + c] = f2bf(src[c * 256 + co]);
}

// ---------------------------------------------------------------------------
// text stage (verified R3): bf16 outputs k_rot [bh][s][hd], v_t [bh][hd][s].
// ---------------------------------------------------------------------------
__global__ __launch_bounds__(256) void text_stage(
    const float* __restrict__ text,
    const float* __restrict__ k_w, const float* __restrict__ k_b,
    const float* __restrict__ v_w, const float* __restrict__ v_b,
    const float* __restrict__ m1_w, const float* __restrict__ m1_b,
    const float* __restrict__ m2_w, const float* __restrict__ m2_b,
    short* __restrict__ k_rot, short* __restrict__ v_t)
{
    __shared__ float t_s[4][TD_];
    __shared__ float h_s[4][C_];
    __shared__ float k_s[4][C_];
    const int tid = threadIdx.x;
    const int token0 = blockIdx.x * 4;

    for (int i = tid; i < 4 * TD_; i += 256)
        t_s[i >> 9][i & (TD_ - 1)] = text[(size_t)token0 * TD_ + i];
    __syncthreads();

    float kv[4], vv[4], hv[4];
#pragma unroll
    for (int tk = 0; tk < 4; ++tk) { kv[tk] = k_b[tid]; vv[tk] = v_b[tid]; hv[tk] = m1_b[tid]; }

    for (int j = 0; j < TD_; ++j) {
        float wk = k_w[j * C_ + tid];
        float wvv = v_w[j * C_ + tid];
        float wm = m1_w[j * C_ + tid];
#pragma unroll
        for (int tk = 0; tk < 4; ++tk) {
            float tj = t_s[tk][j];
            kv[tk] += tj * wk; vv[tk] += tj * wvv; hv[tk] += tj * wm;
        }
    }
#pragma unroll
    for (int tk = 0; tk < 4; ++tk) {
        float h = hv[tk];
        h = 0.5f * h * (1.0f + erff(h * 0.70710678118654752f));
        h_s[tk][tid] = h;
        k_s[tk][tid] = kv[tk];
    }
    __syncthreads();

    float ph[4];
#pragma unroll
    for (int tk = 0; tk < 4; ++tk) ph[tk] = m2_b[tid];
    for (int j = 0; j < C_; ++j) {
        float wm = m2_w[j * C_ + tid];
#pragma unroll
        for (int tk = 0; tk < 4; ++tk) ph[tk] += h_s[tk][j] * wm;
    }

    const int t = tid & (HD - 1);
    const int nh = tid >> 5;
#pragma unroll
    for (int tk = 0; tk < 4; ++tk) {
        int token = token0 + tk;
        int b = token >> 8, s = token & (S_ - 1);
        float partner = (t < 16) ? -k_s[tk][tid + 16] : k_s[tk][tid - 16];
        float kr = kv[tk] * cosf(ph[tk]) + partner * sinf(ph[tk]);
        k_rot[((size_t)(b * NHD + nh) * S_ + s) * HD + t] = f2bf(kr);
        v_t[((size_t)(b * NHD + nh) * HD + t) * S_ + s]   = f2bf(vv[tk]);
    }
}

// 3D rope freq (verified R3)
__device__ __forceinline__ float freq3d(int t, int n){
    int d = n >> 10, h = (n >> 5) & 31, w = n & 31;
    float pos, ex;
    if (t < 10)      { pos = (float)d; ex = (float)(2 * (t % 5)) * 0.1f; }
    else if (t < 20) { pos = (float)h; ex = (float)(2 * ((t - 10) % 5)) * 0.1f; }
    else             { pos = (float)w; ex = (float)(2 * ((t - 20) % 6)) * (1.0f / 12.0f); }
    return pos * expf(-ex * 9.210340371976184f);
}

// ---------------------------------------------------------------------------
// FUSED: qproj + RoPE + attention + oproj. Block = 64 n-rows of one batch,
// 4 waves x 16 rows, zero __syncthreads (all LDS wave-private).
// LDS 52 KB -> 3 blocks/CU. XOR-swizzled on 8-short blocks:
//   Qs [64][256], key = row&7        (RoPE'd Q, [n][co])
//   Pb per-wave [16][128], key=row&7 (exp-scores, one 128-key half at a time)
//   Ot per-wave [16][32], key=(row>>2)^(row&3)  (per-head O, [n][hd])
// ---------------------------------------------------------------------------
__global__ __launch_bounds__(256, 3) void fused_visual(
    const short* __restrict__ fvt, const short* __restrict__ wt_q,
    const float* __restrict__ q_b, const short* __restrict__ k_rot,
    const short* __restrict__ v_t, const short* __restrict__ wt_o,
    const float* __restrict__ o_b, float* __restrict__ out)
{
    __shared__ short Qs[64 * 256];     // 32 KB
    __shared__ short Pb[4 * 16 * 128]; // 16 KB
    __shared__ short Ot[4 * 16 * 32];  // 4 KB
    const int tid = threadIdx.x;
    const int l15 = tid & 15, qd = (tid >> 4) & 3, wv = tid >> 6;
    const int n0 = blockIdx.x * 64;
    const int b = blockIdx.y;
    const f32x4 z4 = {0.f, 0.f, 0.f, 0.f};
    const float scale = 0.17677669529663687f;  // 32^-0.5, folded into Q

    // ---------------- qproj ----------------
    {
        f32x4 acc[16];
#pragma unroll
        for (int i = 0; i < 16; ++i) acc[i] = z4;
        const short* arow = fvt + ((size_t)b * N_ + n0 + wv * 16 + l15) * 256 + qd * 8;
#pragma unroll
        for (int c0 = 0; c0 < 256; c0 += 32) {
            bf16x8 af = *(const bf16x8*)(arow + c0);
#pragma unroll
            for (int nt = 0; nt < 16; ++nt) {
                bf16x8 bq = *(const bf16x8*)&wt_q[(size_t)(nt * 16 + l15) * 256 + c0 + qd * 8];
                acc[nt] = MFMA16(af, bq, acc[nt]);
            }
        }
        // RoPE -> Qs (swizzled)
#pragma unroll
        for (int r = 0; r < 4; ++r) {
            int row = wv * 16 + qd * 4 + r;
            int n = n0 + row;
            int key = row & 7;
            float f1 = freq3d(l15, n), f2 = freq3d(l15 + 16, n);
            float c1 = cosf(f1), s1 = sinf(f1), c2 = cosf(f2), s2 = sinf(f2);
#pragma unroll
            for (int hh = 0; hh < 8; ++hh) {
                float x1 = acc[2 * hh][r]     + q_b[hh * 32 + l15];
                float x2 = acc[2 * hh + 1][r] + q_b[hh * 32 + 16 + l15];
                int cb1 = (hh * 4 + (l15 >> 3)) ^ key;
                int cb2 = (hh * 4 + 2 + (l15 >> 3)) ^ key;
                Qs[row * 256 + cb1 * 8 + (l15 & 7)] = f2bf((x1 * c1 - x2 * s1) * scale);
                Qs[row * 256 + cb2 * 8 + (l15 & 7)] = f2bf((x2 * c2 + x1 * s2) * scale);
            }
        }
    }

    // ---------------- attention + accumulated oproj ----------------
    f32x4 acc_co[16];
#pragma unroll
    for (int i = 0; i < 16; ++i) acc_co[i] = z4;
    short* Pw = Pb + wv * 16 * 128;
    short* Ow = Ot + wv * 16 * 32;

#pragma unroll
    for (int h = 0; h < 8; ++h) {
        const short* kbase = k_rot + (size_t)(b * NHD + h) * (S_ * HD);
        const short* vbase = v_t + (size_t)(b * NHD + h) * (S_ * HD);

        bf16x8 aq = *(const bf16x8*)&Qs[(wv * 16 + l15) * 256 + ((h * 4 + qd) ^ (l15 & 7)) * 8];

        float tsum[4] = {0.f, 0.f, 0.f, 0.f};
        f32x4 o0 = z4, o1 = z4;

#pragma unroll
        for (int half = 0; half < 2; ++half) {
            f32x4 sc[8];
#pragma unroll
            for (int st8 = 0; st8 < 8; ++st8) {
                int st = half * 8 + st8;
                bf16x8 bk = *(const bf16x8*)&kbase[(st * 16 + l15) * 32 + qd * 8];
                sc[st8] = MFMA16(aq, bk, z4);
            }
#pragma unroll
            for (int st8 = 0; st8 < 8; ++st8)
#pragma unroll
                for (int r = 0; r < 4; ++r) {
                    sc[st8][r] = __expf(sc[st8][r]);
                    tsum[r] += sc[st8][r];
                }
            // write P half (rows qd*4+r, cols st8*16+l15), swizzled
#pragma unroll
            for (int st8 = 0; st8 < 8; ++st8)
#pragma unroll
                for (int r = 0; r < 4; ++r) {
                    int row = qd * 4 + r;
                    int cb = (st8 * 2 + (l15 >> 3)) ^ (row & 7);
                    Pw[row * 128 + cb * 8 + (l15 & 7)] = f2bf(sc[st8][r]);
                }
            // PV over this half's 128 keys
#pragma unroll
            for (int kt = 0; kt < 4; ++kt) {
                int cb = (kt * 4 + qd) ^ (l15 & 7);
                bf16x8 pa = *(const bf16x8*)&Pw[l15 * 128 + cb * 8];
                int scol = half * 128 + kt * 32 + qd * 8;
                bf16x8 v0 = *(const bf16x8*)&vbase[(size_t)l15 * 256 + scol];
                bf16x8 v1 = *(const bf16x8*)&vbase[(size_t)(l15 + 16) * 256 + scol];
                o0 = MFMA16(pa, v0, o0);
                o1 = MFMA16(pa, v1, o1);
            }
        }
        float il[4];
#pragma unroll
        for (int r = 0; r < 4; ++r) {
            float t = tsum[r];
            t += __shfl_xor(t, 1); t += __shfl_xor(t, 2);
            t += __shfl_xor(t, 4); t += __shfl_xor(t, 8);
            il[r] = 1.f / t;
        }
        // O -> Ot (rows n-local, cols hd), swizzle key = (row>>2)^(row&3)
#pragma unroll
        for (int r = 0; r < 4; ++r) {
            int row = qd * 4 + r;
            int key = qd ^ r;
            int cb1 = ((l15 >> 3) ^ key) & 3;
            int cb2 = ((2 + (l15 >> 3)) ^ key) & 3;
            Ow[row * 32 + cb1 * 8 + (l15 & 7)] = f2bf(o0[r] * il[r]);
            Ow[row * 32 + cb2 * 8 + (l15 & 7)] = f2bf(o1[r] * il[r]);
        }
        bf16x8 bo = *(const bf16x8*)&Ow[l15 * 32 + ((qd ^ ((l15 >> 2) ^ (l15 & 3))) & 3) * 8];
#pragma unroll
        for (int mt = 0; mt < 16; ++mt) {
            bf16x8 ao = *(const bf16x8*)&wt_o[(size_t)(mt * 16 + l15) * 256 + h * 32 + qd * 8];
            acc_co[mt] = MFMA16(ao, bo, acc_co[mt]);
        }
    }

    // ---------------- epilogue: rows = co, cols = n -> coalesced stores ----
#pragma unroll
    for (int mt = 0; mt < 16; ++mt)
#pragma unroll
        for (int r = 0; r < 4; ++r) {
            int co = mt * 16 + qd * 4 + r;
            out[(size_t)(b * C_ + co) * N_ + n0 + wv * 16 + l15] = acc_co[mt][r] + o_b[co];
        }
}

// ---------------------------------------------------------------------------
extern "C" void kernel_launch(void* const* d_in, const int* in_sizes, int n_in,
                              void* d_out, int out_size, void* d_ws, size_t ws_size,
                              hipStream_t stream) {
    (void)in_sizes; (void)n_in; (void)out_size; (void)ws_size;
    const float* fv   = (const float*)d_in[0];
    const float* text = (const float*)d_in[1];
    const float* q_w  = (const float*)d_in[2];
    const float* q_b  = (const float*)d_in[3];
    const float* k_w  = (const float*)d_in[4];
    const float* k_b  = (const float*)d_in[5];
    const float* v_w  = (const float*)d_in[6];
    const float* v_b  = (const float*)d_in[7];
    const float* o_w  = (const float*)d_in[8];
    const float* o_b  = (const float*)d_in[9];
    const float* m1_w = (const float*)d_in[10];
    const float* m1_b = (const float*)d_in[11];
    const float* m2_w = (const float*)d_in[12];
    const float* m2_b = (const float*)d_in[13];
    float* out = (float*)d_out;

    short* wsS   = (short*)d_ws;
    short* k_rot = wsS;                      // 131072
    short* v_t   = wsS + 131072;             // 131072
    short* wt_q  = wsS + 262144;             // 65536
    short* wt_o  = wsS + 327680;             // 65536
    short* fvt   = wsS + 393216;             // 16777216 (33.5 MB)

    hipLaunchKernelGGL(prep_fvt, dim3(256, 4, 2), dim3(256), 0, stream, fv, fvt);
    hipLaunchKernelGGL(prep_w, dim3(512), dim3(256), 0, stream, q_w, o_w, wt_q, wt_o);
    hipLaunchKernelGGL(text_stage, dim3(128), dim3(256), 0, stream,
                       text, k_w, k_b, v_w, v_b, m1_w, m1_b, m2_w, m2_b, k_rot, v_t);
    hipLaunchKernelGGL(fused_visual, dim3(512, 2), dim3(256), 0, stream,
                       fvt, wt_q, q_b, k_rot, v_t, wt_o, o_b, out);
}

// Round 6
// 409.420 us; speedup vs baseline: 1.5572x; 1.5572x over previous
//
#include <hip/hip_runtime.h>
#include <hip/hip_bf16.h>

#define NHD 8
#define HD  32
#define C_  256
#define TD_ 512
#define S_  256
#define N_  32768   // D*H*W
#define B_  2

typedef short bf16x8 __attribute__((ext_vector_type(8)));
typedef short bf16x4 __attribute__((ext_vector_type(4)));
typedef float f32x4  __attribute__((ext_vector_type(4)));

#define MFMA16(a,b,c) __builtin_amdgcn_mfma_f32_16x16x32_bf16(a,b,c,0,0,0)

__device__ __forceinline__ short f2bf(float f){
    __hip_bfloat16 h = __float2bfloat16(f);
    return *reinterpret_cast<short*>(&h);
}

// ---------------------------------------------------------------------------
// prep_fvtf: fv f32 [b][c][n] -> fragment-ordered bf16
//   fvtf[b][ntile][cc][lane][8] ; element = fv[b][cc*32+(lane>>4)*8+j][ntile*16+(lane&15)]
// Per block: 64c x 128n tile via swizzled LDS (R5-verified transpose core).
// ---------------------------------------------------------------------------
__global__ __launch_bounds__(256) void prep_fvtf(
    const float* __restrict__ fv, short* __restrict__ fvtf)
{
    __shared__ short Ts[64 * 128];   // 16 KB
    const int t = threadIdx.x;
    const int n0 = blockIdx.x * 128, c0 = blockIdx.y * 64, b = blockIdx.z;

#pragma unroll
    for (int i = 0; i < 8; ++i) {
        int c_loc = (t >> 5) + 8 * i;            // 0..63
        int u = t & 31;                           // n-unit (4 floats)
        float4 v = *(const float4*)&fv[(size_t)(b * C_ + c0 + c_loc) * N_ + n0 + u * 4];
        int up = u ^ (c_loc & 31);
        bf16x4 s4 = { f2bf(v.x), f2bf(v.y), f2bf(v.z), f2bf(v.w) };
        *(bf16x4*)&Ts[c_loc * 128 + up * 4] = s4;
    }
    __syncthreads();
#pragma unroll
    for (int p = 0; p < 4; ++p) {
        int idx = p * 256 + t;                    // 0..1023
        int lane = idx & 63, ccl = (idx >> 6) & 1, ntl = idx >> 7;
        bf16x8 r;
#pragma unroll
        for (int k = 0; k < 8; ++k) {
            int c = ccl * 32 + (lane >> 4) * 8 + k;
            int n = ntl * 16 + (lane & 15);
            r[k] = Ts[c * 128 + ((n >> 2) ^ (c & 31)) * 4 + (n & 3)];
        }
        size_t chunk = ((size_t)b * 2048 + (n0 >> 4) + ntl) * 8 + (c0 >> 5) + ccl;
        *(bf16x8*)&fvtf[chunk * 512 + lane * 8] = r;
    }
}

// ---------------------------------------------------------------------------
// prep_wf: q_w/o_w fp32 [c][co] -> fragment-ordered bf16
//   wqf[nt][cc][lane][8] = q_w[cc*32+(lane>>4)*8+j][nt*16+(lane&15)]
//   wof[h][mt][lane][8]  = o_w[h*32+(lane>>4)*8+j][mt*16+(lane&15)]
// ---------------------------------------------------------------------------
__global__ __launch_bounds__(256) void prep_wf(
    const float* __restrict__ qw, const float* __restrict__ ow,
    short* __restrict__ wqf, short* __restrict__ wof)
{
    int gid = blockIdx.x * 256 + threadIdx.x;   // 64 blocks -> 16384
    int m = gid >> 13;
    int rest = gid & 8191;
    const float* src = m ? ow : qw;
    short* dst = m ? wof : wqf;
    int lane = rest & 63;
    int l15 = lane & 15, qd = lane >> 4;
    int cbase, co;
    if (m == 0) { int nt = rest >> 9, cc = (rest >> 6) & 7; cbase = cc * 32 + qd * 8; co = nt * 16 + l15; }
    else        { int hm = rest >> 6; cbase = (hm >> 4) * 32 + qd * 8; co = (hm & 15) * 16 + l15; }
    bf16x8 r;
#pragma unroll
    for (int j = 0; j < 8; ++j) r[j] = f2bf(src[(size_t)(cbase + j) * 256 + co]);
    *(bf16x8*)&dst[(size_t)rest * 8] = r;
}

// ---------------------------------------------------------------------------
// text stage (verified math): outputs fragment-ordered
//   kf[bh][st][lane][8] = K_rot[bh][st*16+(lane&15)][(lane>>4)*8+j]
//   vf[bh][kt][e][lane][8] = V[bh][kt*32+(lane>>4)*8+j][e*16+(lane&15)]
// ---------------------------------------------------------------------------
__global__ __launch_bounds__(256) void text_stage(
    const float* __restrict__ text,
    const float* __restrict__ k_w, const float* __restrict__ k_b,
    const float* __restrict__ v_w, const float* __restrict__ v_b,
    const float* __restrict__ m1_w, const float* __restrict__ m1_b,
    const float* __restrict__ m2_w, const float* __restrict__ m2_b,
    short* __restrict__ kf, short* __restrict__ vf)
{
    __shared__ float t_s[4][TD_];
    __shared__ float h_s[4][C_];
    __shared__ float k_s[4][C_];
    const int tid = threadIdx.x;
    const int token0 = blockIdx.x * 4;

    for (int i = tid; i < 4 * TD_; i += 256)
        t_s[i >> 9][i & (TD_ - 1)] = text[(size_t)token0 * TD_ + i];
    __syncthreads();

    float kv[4], vv[4], hv[4];
#pragma unroll
    for (int tk = 0; tk < 4; ++tk) { kv[tk] = k_b[tid]; vv[tk] = v_b[tid]; hv[tk] = m1_b[tid]; }

    for (int j = 0; j < TD_; ++j) {
        float wk = k_w[j * C_ + tid];
        float wvv = v_w[j * C_ + tid];
        float wm = m1_w[j * C_ + tid];
#pragma unroll
        for (int tk = 0; tk < 4; ++tk) {
            float tj = t_s[tk][j];
            kv[tk] += tj * wk; vv[tk] += tj * wvv; hv[tk] += tj * wm;
        }
    }
#pragma unroll
    for (int tk = 0; tk < 4; ++tk) {
        float h = hv[tk];
        h = 0.5f * h * (1.0f + erff(h * 0.70710678118654752f));
        h_s[tk][tid] = h;
        k_s[tk][tid] = kv[tk];
    }
    __syncthreads();

    float ph[4];
#pragma unroll
    for (int tk = 0; tk < 4; ++tk) ph[tk] = m2_b[tid];
    for (int j = 0; j < C_; ++j) {
        float wm = m2_w[j * C_ + tid];
#pragma unroll
        for (int tk = 0; tk < 4; ++tk) ph[tk] += h_s[tk][j] * wm;
    }

    const int t = tid & (HD - 1);
    const int nh = tid >> 5;
#pragma unroll
    for (int tk = 0; tk < 4; ++tk) {
        int token = token0 + tk;
        int b = token >> 8, s = token & (S_ - 1);
        int bh = b * NHD + nh;
        float partner = (t < 16) ? -k_s[tk][tid + 16] : k_s[tk][tid - 16];
        float kr = kv[tk] * cosf(ph[tk]) + partner * sinf(ph[tk]);
        kf[(((size_t)bh * 16 + (s >> 4)) * 64 + (t >> 3) * 16 + (s & 15)) * 8 + (t & 7)] = f2bf(kr);
        vf[((((size_t)bh * 8 + (s >> 5)) * 2 + (t >> 4)) * 64 + ((s >> 3) & 3) * 16 + (t & 15)) * 8 + (s & 7)] = f2bf(vv[tk]);
    }
}

// 3D rope freq (verified R3/R4)
__device__ __forceinline__ float freq3d(int t, int n){
    int d = n >> 10, h = (n >> 5) & 31, w = n & 31;
    float pos, ex;
    if (t < 10)      { pos = (float)d; ex = (float)(2 * (t % 5)) * 0.1f; }
    else if (t < 20) { pos = (float)h; ex = (float)(2 * ((t - 10) % 5)) * 0.1f; }
    else             { pos = (float)w; ex = (float)(2 * ((t - 20) % 6)) * (1.0f / 12.0f); }
    return pos * expf(-ex * 9.210340371976184f);
}

// ---------------------------------------------------------------------------
// FUSED: qproj + RoPE + attention + oproj. Block = 64 n-rows of one batch,
// 4 waves x M=16, zero __syncthreads (LDS wave-private; per-wave DS ops are
// in-order so buffer reuse across quarters/heads is safe).
// ALL global loads are fragment-ordered: one contiguous 1-KB wave transaction.
// LDS 47 KB -> 3 blocks/CU. Head loop NOT unrolled (R5 spill lesson).
// ---------------------------------------------------------------------------
__global__ __launch_bounds__(256, 3) void fused_visual(
    const short* __restrict__ fvtf, const short* __restrict__ wqf,
    const float* __restrict__ q_b, const short* __restrict__ kf,
    const short* __restrict__ vf, const short* __restrict__ wof,
    const float* __restrict__ o_b, float* __restrict__ out)
{
    __shared__ __align__(16) short Qs[64 * 264];    // 33792 B, pitch 528 B
    __shared__ __align__(16) short Pb[4 * 16 * 72]; //  9216 B, pitch 144 B
    __shared__ __align__(16) short Ot[4 * 16 * 40]; //  5120 B, pitch  80 B
    const int tid = threadIdx.x;
    const int lane = tid & 63;
    const int l15 = tid & 15, qd = (tid >> 4) & 3, wv = tid >> 6;
    const int n0 = blockIdx.x * 64;
    const int b = blockIdx.y;
    const f32x4 z4 = {0.f, 0.f, 0.f, 0.f};
    const float scale = 0.17677669529663687f;  // 32^-0.5, folded into Q

    // ---------------- qproj ----------------
    {
        f32x4 acc[16];
#pragma unroll
        for (int i = 0; i < 16; ++i) acc[i] = z4;
        const short* abase = fvtf + ((size_t)b * 2048 + (n0 >> 4) + wv) * 8 * 512 + lane * 8;
#pragma unroll
        for (int cc = 0; cc < 8; ++cc) {
            bf16x8 af = *(const bf16x8*)(abase + cc * 512);
#pragma unroll
            for (int nt = 0; nt < 16; ++nt) {
                bf16x8 bq = *(const bf16x8*)&wqf[((nt * 8 + cc) * 64 + lane) * 8];
                acc[nt] = MFMA16(af, bq, acc[nt]);
            }
        }
        // RoPE -> Qs (rows wave-private)
#pragma unroll
        for (int r = 0; r < 4; ++r) {
            int row = wv * 16 + qd * 4 + r;
            int n = n0 + row;
            float f1 = freq3d(l15, n), f2 = freq3d(l15 + 16, n);
            float c1 = cosf(f1), s1 = sinf(f1), c2 = cosf(f2), s2 = sinf(f2);
#pragma unroll
            for (int hh = 0; hh < 8; ++hh) {
                float x1 = acc[2 * hh][r]     + q_b[hh * 32 + l15];
                float x2 = acc[2 * hh + 1][r] + q_b[hh * 32 + 16 + l15];
                Qs[row * 264 + hh * 32 + l15]      = f2bf((x1 * c1 - x2 * s1) * scale);
                Qs[row * 264 + hh * 32 + 16 + l15] = f2bf((x2 * c2 + x1 * s2) * scale);
            }
        }
    }

    // ---------------- attention + accumulated oproj ----------------
    f32x4 acc_co[16];
#pragma unroll
    for (int i = 0; i < 16; ++i) acc_co[i] = z4;
    short* Pw = Pb + wv * 16 * 72;
    short* Ow = Ot + wv * 16 * 40;

#pragma unroll 1
    for (int h = 0; h < 8; ++h) {
        const int bh = b * NHD + h;
        const short* kbase  = kf  + (size_t)bh * 16 * 512;
        const short* vbase  = vf  + (size_t)bh * 8 * 1024;
        const short* wobase = wof + (size_t)h * 16 * 512;

        bf16x8 aq = *(const bf16x8*)&Qs[(wv * 16 + l15) * 264 + h * 32 + qd * 8];
        float tsum[4] = {0.f, 0.f, 0.f, 0.f};
        f32x4 o0 = z4, o1 = z4;

#pragma unroll
        for (int qt = 0; qt < 4; ++qt) {
            f32x4 sc[4];
#pragma unroll
            for (int s4 = 0; s4 < 4; ++s4) {
                bf16x8 bk = *(const bf16x8*)&kbase[(qt * 4 + s4) * 512 + lane * 8];
                sc[s4] = MFMA16(aq, bk, z4);
            }
#pragma unroll
            for (int s4 = 0; s4 < 4; ++s4)
#pragma unroll
                for (int r = 0; r < 4; ++r) {
                    sc[s4][r] = __expf(sc[s4][r]);
                    tsum[r] += sc[s4][r];
                }
#pragma unroll
            for (int s4 = 0; s4 < 4; ++s4)
#pragma unroll
                for (int r = 0; r < 4; ++r)
                    Pw[(qd * 4 + r) * 72 + s4 * 16 + l15] = f2bf(sc[s4][r]);
#pragma unroll
            for (int ktl = 0; ktl < 2; ++ktl) {
                bf16x8 pa = *(const bf16x8*)&Pw[l15 * 72 + ktl * 32 + qd * 8];
                int kt = qt * 2 + ktl;
                bf16x8 v0 = *(const bf16x8*)&vbase[(kt * 2 + 0) * 512 + lane * 8];
                bf16x8 v1 = *(const bf16x8*)&vbase[(kt * 2 + 1) * 512 + lane * 8];
                o0 = MFMA16(pa, v0, o0);
                o1 = MFMA16(pa, v1, o1);
            }
        }
        float il[4];
#pragma unroll
        for (int r = 0; r < 4; ++r) {
            float t = tsum[r];
            t += __shfl_xor(t, 1); t += __shfl_xor(t, 2);
            t += __shfl_xor(t, 4); t += __shfl_xor(t, 8);
            il[r] = 1.f / t;
        }
#pragma unroll
        for (int r = 0; r < 4; ++r) {
            Ow[(qd * 4 + r) * 40 + l15]      = f2bf(o0[r] * il[r]);
            Ow[(qd * 4 + r) * 40 + 16 + l15] = f2bf(o1[r] * il[r]);
        }
        bf16x8 bo = *(const bf16x8*)&Ow[l15 * 40 + qd * 8];
#pragma unroll
        for (int mt = 0; mt < 16; ++mt) {
            bf16x8 ao = *(const bf16x8*)&wobase[mt * 512 + lane * 8];
            acc_co[mt] = MFMA16(ao, bo, acc_co[mt]);
        }
    }

    // ---------------- epilogue: rows = co, cols = n -> coalesced stores ----
#pragma unroll
    for (int mt = 0; mt < 16; ++mt)
#pragma unroll
        for (int r = 0; r < 4; ++r) {
            int co = mt * 16 + qd * 4 + r;
            out[(size_t)(b * C_ + co) * N_ + n0 + wv * 16 + l15] = acc_co[mt][r] + o_b[co];
        }
}

// ---------------------------------------------------------------------------
extern "C" void kernel_launch(void* const* d_in, const int* in_sizes, int n_in,
                              void* d_out, int out_size, void* d_ws, size_t ws_size,
                              hipStream_t stream) {
    (void)in_sizes; (void)n_in; (void)out_size; (void)ws_size;
    const float* fv   = (const float*)d_in[0];
    const float* text = (const float*)d_in[1];
    const float* q_w  = (const float*)d_in[2];
    const float* q_b  = (const float*)d_in[3];
    const float* k_w  = (const float*)d_in[4];
    const float* k_b  = (const float*)d_in[5];
    const float* v_w  = (const float*)d_in[6];
    const float* v_b  = (const float*)d_in[7];
    const float* o_w  = (const float*)d_in[8];
    const float* o_b  = (const float*)d_in[9];
    const float* m1_w = (const float*)d_in[10];
    const float* m1_b = (const float*)d_in[11];
    const float* m2_w = (const float*)d_in[12];
    const float* m2_b = (const float*)d_in[13];
    float* out = (float*)d_out;

    short* wsS  = (short*)d_ws;
    short* kf   = wsS;                      // 131072 shorts
    short* vf   = wsS + 131072;             // 131072
    short* wqf  = wsS + 262144;             // 65536
    short* wof  = wsS + 327680;             // 65536
    short* fvtf = wsS + 393216;             // 16777216 (33.5 MB)

    hipLaunchKernelGGL(prep_fvtf, dim3(256, 4, 2), dim3(256), 0, stream, fv, fvtf);
    hipLaunchKernelGGL(prep_wf, dim3(64), dim3(256), 0, stream, q_w, o_w, wqf, wof);
    hipLaunchKernelGGL(text_stage, dim3(128), dim3(256), 0, stream,
                       text, k_w, k_b, v_w, v_b, m1_w, m1_b, m2_w, m2_b, kf, vf);
    hipLaunchKernelGGL(fused_visual, dim3(512, 2), dim3(256), 0, stream,
                       fvtf, wqf, q_b, kf, vf, wof, o_b, out);
}

// Round 8
// 370.923 us; speedup vs baseline: 1.7188x; 1.1038x over previous
//
#include <hip/hip_runtime.h>
#include <hip/hip_bf16.h>

#define NHD 8
#define HD  32
#define C_  256
#define TD_ 512
#define S_  256
#define N_  32768   // D*H*W
#define B_  2

typedef short bf16x8 __attribute__((ext_vector_type(8)));
typedef short bf16x4 __attribute__((ext_vector_type(4)));
typedef float f32x4  __attribute__((ext_vector_type(4)));

#define MFMA16(a,b,c) __builtin_amdgcn_mfma_f32_16x16x32_bf16(a,b,c,0,0,0)

__device__ __forceinline__ short f2bf(float f){
    __hip_bfloat16 h = __float2bfloat16(f);
    return *reinterpret_cast<short*>(&h);
}

// ---------------------------------------------------------------------------
// prep_fvtf (verified R6): fv f32 [b][c][n] -> fragment-ordered bf16
//   fvtf[b][ntile][cc][lane][8] = fv[b][cc*32+(lane>>4)*8+j][ntile*16+(lane&15)]
// ---------------------------------------------------------------------------
__global__ __launch_bounds__(256) void prep_fvtf(
    const float* __restrict__ fv, short* __restrict__ fvtf)
{
    __shared__ short Ts[64 * 128];   // 16 KB
    const int t = threadIdx.x;
    const int n0 = blockIdx.x * 128, c0 = blockIdx.y * 64, b = blockIdx.z;

#pragma unroll
    for (int i = 0; i < 8; ++i) {
        int c_loc = (t >> 5) + 8 * i;            // 0..63
        int u = t & 31;                           // n-unit (4 floats)
        float4 v = *(const float4*)&fv[(size_t)(b * C_ + c0 + c_loc) * N_ + n0 + u * 4];
        int up = u ^ (c_loc & 31);
        bf16x4 s4 = { f2bf(v.x), f2bf(v.y), f2bf(v.z), f2bf(v.w) };
        *(bf16x4*)&Ts[c_loc * 128 + up * 4] = s4;
    }
    __syncthreads();
#pragma unroll
    for (int p = 0; p < 4; ++p) {
        int idx = p * 256 + t;                    // 0..1023
        int lane = idx & 63, ccl = (idx >> 6) & 1, ntl = idx >> 7;
        bf16x8 r;
#pragma unroll
        for (int k = 0; k < 8; ++k) {
            int c = ccl * 32 + (lane >> 4) * 8 + k;
            int n = ntl * 16 + (lane & 15);
            r[k] = Ts[c * 128 + ((n >> 2) ^ (c & 31)) * 4 + (n & 3)];
        }
        size_t chunk = ((size_t)b * 2048 + (n0 >> 4) + ntl) * 8 + (c0 >> 5) + ccl;
        *(bf16x8*)&fvtf[chunk * 512 + lane * 8] = r;
    }
}

// ---------------------------------------------------------------------------
// prep_wf (verified R6): q_w/o_w fp32 [c][co] -> fragment-ordered bf16
// ---------------------------------------------------------------------------
__global__ __launch_bounds__(256) void prep_wf(
    const float* __restrict__ qw, const float* __restrict__ ow,
    short* __restrict__ wqf, short* __restrict__ wof)
{
    int gid = blockIdx.x * 256 + threadIdx.x;   // 64 blocks -> 16384
    int m = gid >> 13;
    int rest = gid & 8191;
    const float* src = m ? ow : qw;
    short* dst = m ? wof : wqf;
    int lane = rest & 63;
    int l15 = lane & 15, qd = lane >> 4;
    int cbase, co;
    if (m == 0) { int nt = rest >> 9, cc = (rest >> 6) & 7; cbase = cc * 32 + qd * 8; co = nt * 16 + l15; }
    else        { int hm = rest >> 6; cbase = (hm >> 4) * 32 + qd * 8; co = (hm & 15) * 16 + l15; }
    bf16x8 r;
#pragma unroll
    for (int j = 0; j < 8; ++j) r[j] = f2bf(src[(size_t)(cbase + j) * 256 + co]);
    *(bf16x8*)&dst[(size_t)rest * 8] = r;
}

// ---------------------------------------------------------------------------
// text stage (math verified R6; 1 token/block, 512 blocks — R6's 128-block
// version was a latency-bound ~100+us sink with half the GPU idle).
// Outputs fragment-ordered kf/vf, indexing identical to R6.
// ---------------------------------------------------------------------------
__global__ __launch_bounds__(256) void text_stage(
    const float* __restrict__ text,
    const float* __restrict__ k_w, const float* __restrict__ k_b,
    const float* __restrict__ v_w, const float* __restrict__ v_b,
    const float* __restrict__ m1_w, const float* __restrict__ m1_b,
    const float* __restrict__ m2_w, const float* __restrict__ m2_b,
    short* __restrict__ kf, short* __restrict__ vf)
{
    __shared__ float t_s[TD_];
    __shared__ float h_s[C_];
    __shared__ float k_s[C_];
    const int tid = threadIdx.x;
    const int token = blockIdx.x;      // 0..511

    float2 tt = *(const float2*)&text[(size_t)token * TD_ + tid * 2];
    t_s[tid * 2] = tt.x; t_s[tid * 2 + 1] = tt.y;
    __syncthreads();

    float kv = k_b[tid], vv = v_b[tid], hv = m1_b[tid];
#pragma unroll 4
    for (int j = 0; j < TD_; ++j) {
        float tj = t_s[j];
        kv += tj * k_w[j * C_ + tid];
        vv += tj * v_w[j * C_ + tid];
        hv += tj * m1_w[j * C_ + tid];
    }
    float hg = 0.5f * hv * (1.0f + erff(hv * 0.70710678118654752f));
    h_s[tid] = hg;
    k_s[tid] = kv;
    __syncthreads();

    float ph = m2_b[tid];
#pragma unroll 4
    for (int j = 0; j < C_; ++j)
        ph += h_s[j] * m2_w[j * C_ + tid];

    const int t = tid & (HD - 1);
    const int nh = tid >> 5;
    const int b = token >> 8, s = token & (S_ - 1);
    const int bh = b * NHD + nh;
    float partner = (t < 16) ? -k_s[tid + 16] : k_s[tid - 16];
    float kr = kv * cosf(ph) + partner * sinf(ph);
    kf[(((size_t)bh * 16 + (s >> 4)) * 64 + (t >> 3) * 16 + (s & 15)) * 8 + (t & 7)] = f2bf(kr);
    vf[((((size_t)bh * 8 + (s >> 5)) * 2 + (t >> 4)) * 64 + ((s >> 3) & 3) * 16 + (t & 15)) * 8 + (s & 7)] = f2bf(vv);
}

// 3D rope freq (verified R3/R4/R6)
__device__ __forceinline__ float freq3d(int t, int n){
    int d = n >> 10, h = (n >> 5) & 31, w = n & 31;
    float pos, ex;
    if (t < 10)      { pos = (float)d; ex = (float)(2 * (t % 5)) * 0.1f; }
    else if (t < 20) { pos = (float)h; ex = (float)(2 * ((t - 10) % 5)) * 0.1f; }
    else             { pos = (float)w; ex = (float)(2 * ((t - 20) % 6)) * (1.0f / 12.0f); }
    return pos * expf(-ex * 9.210340371976184f);
}

// ---------------------------------------------------------------------------
// FUSED: qproj + RoPE + attention + oproj. Block = 64 n-rows, 4 waves x M=16,
// zero __syncthreads (LDS wave-private, per-wave DS in-order).
// LDS exactly 40 KB -> 4 blocks/CU (all 1024 blocks co-resident, zero tail):
//   Qs [64][256] xor-swizzled (key=row&7, 8-short blocks)   32 KB
//   Pb per-wave [16][64] xor-swizzled (key=row&7); Ot ALIASES Pb
//     (Ot [16][32], key=row&3) — safe: per-wave DS ops are in-order  8 KB
// aq for head h+1 prefetched before head h's oproj.
// ---------------------------------------------------------------------------
__global__ __launch_bounds__(256, 4) void fused_visual(
    const short* __restrict__ fvtf, const short* __restrict__ wqf,
    const float* __restrict__ q_b, const short* __restrict__ kf,
    const short* __restrict__ vf, const short* __restrict__ wof,
    const float* __restrict__ o_b, float* __restrict__ out)
{
    __shared__ __align__(16) short Qs[64 * 256];   // 32 KB
    __shared__ __align__(16) short Pb[4 * 16 * 64]; // 8 KB (P; Ot aliases)
    const int tid = threadIdx.x;
    const int lane = tid & 63;
    const int l15 = tid & 15, qd = (tid >> 4) & 3, wv = tid >> 6;
    const int n0 = blockIdx.x * 64;
    const int b = blockIdx.y;
    const f32x4 z4 = {0.f, 0.f, 0.f, 0.f};
    const float scale = 0.17677669529663687f;  // 32^-0.5, folded into Q

    // ---------------- qproj ----------------
    {
        f32x4 acc[16];
#pragma unroll
        for (int i = 0; i < 16; ++i) acc[i] = z4;
        const short* abase = fvtf + ((size_t)b * 2048 + (n0 >> 4) + wv) * 8 * 512 + lane * 8;
#pragma unroll
        for (int cc = 0; cc < 8; ++cc) {
            bf16x8 af = *(const bf16x8*)(abase + cc * 512);
#pragma unroll
            for (int nt = 0; nt < 16; ++nt) {
                bf16x8 bq = *(const bf16x8*)&wqf[((nt * 8 + cc) * 64 + lane) * 8];
                acc[nt] = MFMA16(af, bq, acc[nt]);
            }
        }
        // RoPE -> Qs (swizzled, R5-verified scheme)
#pragma unroll
        for (int r = 0; r < 4; ++r) {
            int row = wv * 16 + qd * 4 + r;
            int n = n0 + row;
            int key = row & 7;
            float f1 = freq3d(l15, n), f2 = freq3d(l15 + 16, n);
            float c1 = cosf(f1), s1 = sinf(f1), c2 = cosf(f2), s2 = sinf(f2);
#pragma unroll
            for (int hh = 0; hh < 8; ++hh) {
                float x1 = acc[2 * hh][r]     + q_b[hh * 32 + l15];
                float x2 = acc[2 * hh + 1][r] + q_b[hh * 32 + 16 + l15];
                int cb1 = (hh * 4 + (l15 >> 3)) ^ key;
                int cb2 = (hh * 4 + 2 + (l15 >> 3)) ^ key;
                Qs[row * 256 + cb1 * 8 + (l15 & 7)] = f2bf((x1 * c1 - x2 * s1) * scale);
                Qs[row * 256 + cb2 * 8 + (l15 & 7)] = f2bf((x2 * c2 + x1 * s2) * scale);
            }
        }
    }

    // ---------------- attention + accumulated oproj ----------------
    f32x4 acc_co[16];
#pragma unroll
    for (int i = 0; i < 16; ++i) acc_co[i] = z4;
    short* Pw = Pb + wv * 16 * 64;
    short* Ow = Pw;   // alias (per-wave in-order DS makes this safe)

    bf16x8 aq = *(const bf16x8*)&Qs[(wv * 16 + l15) * 256 + ((qd) ^ (l15 & 7)) * 8];

#pragma unroll 1
    for (int h = 0; h < 8; ++h) {
        const int bh = b * NHD + h;
        const short* kbase  = kf  + (size_t)bh * 16 * 512;
        const short* vbase  = vf  + (size_t)bh * 8 * 1024;
        const short* wobase = wof + (size_t)h * 16 * 512;

        float tsum[4] = {0.f, 0.f, 0.f, 0.f};
        f32x4 o0 = z4, o1 = z4;

#pragma unroll
        for (int qt = 0; qt < 4; ++qt) {
            f32x4 sc[4];
#pragma unroll
            for (int s4 = 0; s4 < 4; ++s4) {
                bf16x8 bk = *(const bf16x8*)&kbase[(qt * 4 + s4) * 512 + lane * 8];
                sc[s4] = MFMA16(aq, bk, z4);
            }
#pragma unroll
            for (int s4 = 0; s4 < 4; ++s4)
#pragma unroll
                for (int r = 0; r < 4; ++r) {
                    sc[s4][r] = __expf(sc[s4][r]);
                    tsum[r] += sc[s4][r];
                }
#pragma unroll
            for (int s4 = 0; s4 < 4; ++s4)
#pragma unroll
                for (int r = 0; r < 4; ++r) {
                    int row = qd * 4 + r;
                    Pw[row * 64 + ((s4 * 2 + (l15 >> 3)) ^ (row & 7)) * 8 + (l15 & 7)] = f2bf(sc[s4][r]);
                }
#pragma unroll
            for (int ktl = 0; ktl < 2; ++ktl) {
                bf16x8 pa = *(const bf16x8*)&Pw[l15 * 64 + ((ktl * 4 + qd) ^ (l15 & 7)) * 8];
                int kt = qt * 2 + ktl;
                bf16x8 v0 = *(const bf16x8*)&vbase[(kt * 2 + 0) * 512 + lane * 8];
                bf16x8 v1 = *(const bf16x8*)&vbase[(kt * 2 + 1) * 512 + lane * 8];
                o0 = MFMA16(pa, v0, o0);
                o1 = MFMA16(pa, v1, o1);
            }
        }
        float il[4];
#pragma unroll
        for (int r = 0; r < 4; ++r) {
            float t = tsum[r];
            t += __shfl_xor(t, 1); t += __shfl_xor(t, 2);
            t += __shfl_xor(t, 4); t += __shfl_xor(t, 8);
            il[r] = 1.f / t;
        }
        // O -> Ot (aliased in Pw), key = row&3
#pragma unroll
        for (int r = 0; r < 4; ++r) {
            int row = qd * 4 + r;
            int key = row & 3;
            Ow[row * 32 + (((l15 >> 3) ^ key) & 3) * 8 + (l15 & 7)]       = f2bf(o0[r] * il[r]);
            Ow[row * 32 + (((2 + (l15 >> 3)) ^ key) & 3) * 8 + (l15 & 7)] = f2bf(o1[r] * il[r]);
        }
        // prefetch next head's aq (hides LDS latency behind oproj MFMAs)
        bf16x8 aq_n = *(const bf16x8*)&Qs[(wv * 16 + l15) * 256 + ((((h + 1) & 7) * 4 + qd) ^ (l15 & 7)) * 8];
        bf16x8 bo = *(const bf16x8*)&Ow[l15 * 32 + ((qd ^ (l15 & 3)) & 3) * 8];
#pragma unroll
        for (int mt = 0; mt < 16; ++mt) {
            bf16x8 ao = *(const bf16x8*)&wobase[mt * 512 + lane * 8];
            acc_co[mt] = MFMA16(ao, bo, acc_co[mt]);
        }
        aq = aq_n;
    }

    // ---------------- epilogue: rows = co, cols = n -> coalesced stores ----
#pragma unroll
    for (int mt = 0; mt < 16; ++mt)
#pragma unroll
        for (int r = 0; r < 4; ++r) {
            int co = mt * 16 + qd * 4 + r;
            out[(size_t)(b * C_ + co) * N_ + n0 + wv * 16 + l15] = acc_co[mt][r] + o_b[co];
        }
}

// ---------------------------------------------------------------------------
extern "C" void kernel_launch(void* const* d_in, const int* in_sizes, int n_in,
                              void* d_out, int out_size, void* d_ws, size_t ws_size,
                              hipStream_t stream) {
    (void)in_sizes; (void)n_in; (void)out_size; (void)ws_size;
    const float* fv   = (const float*)d_in[0];
    const float* text = (const float*)d_in[1];
    const float* q_w  = (const float*)d_in[2];
    const float* q_b  = (const float*)d_in[3];
    const float* k_w  = (const float*)d_in[4];
    const float* k_b  = (const float*)d_in[5];
    const float* v_w  = (const float*)d_in[6];
    const float* v_b  = (const float*)d_in[7];
    const float* o_w  = (const float*)d_in[8];
    const float* o_b  = (const float*)d_in[9];
    const float* m1_w = (const float*)d_in[10];
    const float* m1_b = (const float*)d_in[11];
    const float* m2_w = (const float*)d_in[12];
    const float* m2_b = (const float*)d_in[13];
    float* out = (float*)d_out;

    short* wsS  = (short*)d_ws;
    short* kf   = wsS;                      // 131072 shorts
    short* vf   = wsS + 131072;             // 131072
    short* wqf  = wsS + 262144;             // 65536
    short* wof  = wsS + 327680;             // 65536
    short* fvtf = wsS + 393216;             // 16777216 (33.5 MB)

    hipLaunchKernelGGL(prep_fvtf, dim3(256, 4, 2), dim3(256), 0, stream, fv, fvtf);
    hipLaunchKernelGGL(prep_wf, dim3(64), dim3(256), 0, stream, q_w, o_w, wqf, wof);
    hipLaunchKernelGGL(text_stage, dim3(512), dim3(256), 0, stream,
                       text, k_w, k_b, v_w, v_b, m1_w, m1_b, m2_w, m2_b, kf, vf);
    hipLaunchKernelGGL(fused_visual, dim3(512, 2), dim3(256), 0, stream,
                       fvtf, wqf, q_b, kf, vf, wof, o_b, out);
}